// Round 2
// 180.050 us; speedup vs baseline: 1.0241x; 1.0241x over previous
//
#include <hip/hip_runtime.h>

// MHSA B=8 N=1024 D=768 H=12 Hd=64. Round 10 = round 9 with the lane
// algebra fixed (round 9 never got benched — container failure — but
// offline re-derivation found 3 bugs):
//  - permlane32_swap diagonal: swap(a,b) returns {a',b'} with
//    a'[hi]=b[lo], b'[lo]=a[hi]. P-frag word0 = swap(X0,Y0)[0],
//    word2 = swap(X0,Y0)[1] (round 9 used swap(Y0,X0) + wrong outputs,
//    which is the transposed-half diagonal).
//  - same fix in the epilogue d-interleave swaps.
//  - epilogue store address now includes the wave offset (q = w*32+l31).
// Structure unchanged: attention on 32x32x16 MFMA, S^T = K.Q, P
// fragments assembled fully in-register (no P LDS scratch, no lgkm
// drain), no epilogue LDS, Q staged through dead parity-1 dbuf halves
// (LDS 32 KB). qkv/proj/prep identical to round 8.

#define B_   8
#define N_   1024
#define D_   768
#define H_   12
#define HD_  64

typedef __attribute__((ext_vector_type(4))) float f32x4;
typedef __attribute__((ext_vector_type(16))) float f32x16;
typedef __attribute__((ext_vector_type(8))) short bf16x8;
typedef __attribute__((ext_vector_type(2))) unsigned int u32x2;
typedef __attribute__((ext_vector_type(4))) unsigned int u32x4;

__device__ __forceinline__ unsigned short f2bf(float f) {
    unsigned int u = __float_as_uint(f);
    u += 0x7fff + ((u >> 16) & 1);            // RNE
    return (unsigned short)(u >> 16);
}
__device__ __forceinline__ unsigned int pk2(float a, float b) {
    return (unsigned int)f2bf(a) | ((unsigned int)f2bf(b) << 16);
}
// truncating bf16 pack via v_perm_b32 (low16 = a, high16 = b)
__device__ __forceinline__ unsigned int pk2t(float a, float b) {
    return __builtin_amdgcn_perm(__float_as_uint(b), __float_as_uint(a), 0x07060302u);
}
__device__ __forceinline__ float truncbf(float f) {
    return __uint_as_float(__float_as_uint(f) & 0xFFFF0000u);
}
__device__ __forceinline__ void gl_lds16(const void* g, void* l) {
    __builtin_amdgcn_global_load_lds(
        (const __attribute__((address_space(1))) unsigned int*)g,
        (__attribute__((address_space(3))) unsigned int*)l, 16, 0, 0);
}
#define MFMA(a, b, c)   __builtin_amdgcn_mfma_f32_16x16x32_bf16(a, b, c, 0, 0, 0)
#define MFMA32(a, b, c) __builtin_amdgcn_mfma_f32_32x32x16_bf16(a, b, c, 0, 0, 0)
#define BAR() do { __asm__ volatile("" ::: "memory"); \
    __builtin_amdgcn_s_barrier(); \
    __asm__ volatile("" ::: "memory"); } while (0)
#define WAITVM(n) do { __asm__ volatile("" ::: "memory"); \
    __builtin_amdgcn_s_waitcnt(0xF70 | (n)); \
    __asm__ volatile("" ::: "memory"); } while (0)
#define WAITLGKM() __asm__ volatile("s_waitcnt lgkmcnt(0)" ::: "memory")

// ---------------------------------------------------------------------------
// prep: XB / WQT / WPT in slab order (unchanged).
// ---------------------------------------------------------------------------
__global__ __launch_bounds__(256) void prep_kernel(
    const float* __restrict__ x, const float* __restrict__ wqkv,
    const float* __restrict__ wproj,
    unsigned short* __restrict__ XB, unsigned short* __restrict__ WQT,
    unsigned short* __restrict__ WPT)
{
    const int bid = blockIdx.x;
    const int tid = threadIdx.x;
    if (bid < 3072) {                       // XB
        int id = bid * 256 + tid;
        int r  = id & 127;
        int kc = (id >> 7) & 7;
        int ks = (id >> 10) % 12;
        int nt = id / 12288;
        const float* src = x + (size_t)(nt * 128 + r) * 768 + ks * 64 + kc * 8;
        float4 f0 = *(const float4*)src;
        float4 f1 = *(const float4*)(src + 4);
        uint4 o;
        o.x = pk2(f0.x, f0.y); o.y = pk2(f0.z, f0.w);
        o.z = pk2(f1.x, f1.y); o.w = pk2(f1.z, f1.w);
        *(uint4*)&XB[(size_t)id * 8] = o;
    } else if (bid < 3936) {                // WQT
        int id = (bid - 3072) * 256 + tid;
        int fr = id & 127;
        int kc = (id >> 7) & 7;
        int ks = (id >> 10) % 12;
        int mt = id / 12288;
        float v[8];
#pragma unroll
        for (int j = 0; j < 8; ++j)
            v[j] = wqkv[(size_t)(ks * 64 + kc * 8 + j) * 2304 + mt * 128 + fr];
        uint4 o;
        o.x = pk2(v[0], v[1]); o.y = pk2(v[2], v[3]);
        o.z = pk2(v[4], v[5]); o.w = pk2(v[6], v[7]);
        *(uint4*)&WQT[(size_t)id * 8] = o;
    } else {                                // WPT
        int id = (bid - 3936) * 256 + tid;
        int fr = id & 63;
        int kc = (id >> 6) & 7;
        int ks = (id >> 9) % 12;
        int nt = id / 6144;
        float v[8];
#pragma unroll
        for (int j = 0; j < 8; ++j)
            v[j] = wproj[(size_t)(ks * 64 + kc * 8 + j) * 768 + nt * 64 + fr];
        uint4 o;
        o.x = pk2(v[0], v[1]); o.y = pk2(v[2], v[3]);
        o.z = pk2(v[4], v[5]); o.w = pk2(v[6], v[7]);
        *(uint4*)&WPT[(size_t)id * 8] = o;
    }
}

// ---------------------------------------------------------------------------
// QKV: C^T = Wt . x ; tile 128x128, BK=32 dbuf pipeline; LDS-transposed
// coalesced epilogue. Q pre-scaled by 0.125*log2(e). (unchanged)
// ---------------------------------------------------------------------------
__global__ __launch_bounds__(256, 4) void qkv_gemm(
    const unsigned short* __restrict__ XB,
    const unsigned short* __restrict__ WQT,
    const float* __restrict__ bias,
    unsigned short* __restrict__ QS,   // [bh][qt] slab(128), k=d (scaled)
    unsigned short* __restrict__ KS,   // [bh][kt] slab(64), k=d
    unsigned short* __restrict__ VS)   // [bh][kt] slab(64): rows=d, k=key
{
    __shared__ __align__(16) unsigned short sm[16384];  // 32 KB

    const int tid = threadIdx.x;
    const int w = tid >> 6, lane = tid & 63;
    const int l15 = lane & 15, quad = lane >> 4;
    const int mt = blockIdx.x >> 6;   // 0..17 feat tile
    const int nt = blockIdx.x & 63;   // 0..63 token tile
    const int m0w = (w & 1) * 64, n0w = (w >> 1) * 64;
    const float CS = 0.18033688f;     // 0.125 * log2(e)

    char* smb = (char*)sm;
    const char* baseA = (const char*)(WQT + (size_t)(mt * 12) * 8192);
    const char* baseB = (const char*)(XB  + (size_t)(nt * 12) * 8192);

    auto issue = [&](int ks) {
        const char* sA = baseA + ks * 8192;
        const char* sB = baseB + ks * 8192;
        const int pb = ks & 1;
#pragma unroll
        for (int i = 0; i < 2; ++i) {
            const int c = w * 2 + i;
            gl_lds16(sA + (c * 64 + lane) * 16, smb + pb * 8192 + c * 1024);
            gl_lds16(sB + (c * 64 + lane) * 16, smb + 16384 + pb * 8192 + c * 1024);
        }
    };

    f32x4 acc[4][4];
    const f32x4 z = {0.f, 0.f, 0.f, 0.f};
#pragma unroll
    for (int t = 0; t < 4; ++t)
#pragma unroll
        for (int u = 0; u < 4; ++u) acc[t][u] = z;

    issue(0);
    for (int ks = 0; ks < 24; ++ks) {
        BAR();
        if (ks < 23) { issue(ks + 1); WAITVM(4); } else { WAITVM(0); }
        BAR();
        const unsigned short* Ab = sm + (ks & 1) * 4096;
        const unsigned short* Bb = sm + 8192 + (ks & 1) * 4096;
        bf16x8 af[4], bfv[4];
#pragma unroll
        for (int t = 0; t < 4; ++t)
            af[t] = *(const bf16x8*)(Ab + (quad * 128 + m0w + t * 16 + l15) * 8);
#pragma unroll
        for (int u = 0; u < 4; ++u)
            bfv[u] = *(const bf16x8*)(Bb + (quad * 128 + n0w + u * 16 + l15) * 8);
#pragma unroll
        for (int t = 0; t < 4; ++t)
#pragma unroll
            for (int u = 0; u < 4; ++u)
                acc[t][u] = MFMA(af[t], bfv[u], acc[t][u]);
    }

    const int part = mt / 6;   // 0=Q 1=K 2=V (uniform per block)
    BAR();                     // all waves done with staged LDS

    // ---- write accumulators to swizzled LDS tile ----
#pragma unroll
    for (int t = 0; t < 4; ++t) {
        int d = m0w + t * 16 + quad * 4;          // feat-in-tile 0..127
        float4 bv = *(const float4*)&bias[part * 768 + (mt % 6) * 128 + d];
#pragma unroll
        for (int u = 0; u < 4; ++u) {
            int tok = n0w + u * 16 + l15;         // tok-in-tile 0..127
            f32x4 a = acc[t][u];
            float v0 = a[0] + bv.x, v1 = a[1] + bv.y;
            float v2 = a[2] + bv.z, v3 = a[3] + bv.w;
            if (part == 0) { v0 *= CS; v1 *= CS; v2 *= CS; v3 *= CS; }
            if (part < 2) {
                unsigned off = tok * 256 + (((unsigned)(d * 2)) ^ ((tok & 7) << 4));
                uint2 pp; pp.x = pk2(v0, v1); pp.y = pk2(v2, v3);
                *(uint2*)(smb + off) = pp;
            } else {
                float vv[4] = {v0, v1, v2, v3};
#pragma unroll
                for (int r4 = 0; r4 < 4; ++r4) {
                    int dd = d + r4;
                    unsigned off = dd * 256 + (((unsigned)(tok * 2)) ^ ((dd & 7) << 4));
                    *(unsigned short*)(smb + off) = f2bf(vv[r4]);
                }
            }
        }
    }
    BAR();

    // ---- coalesced read-out + global store ----
    const int b = nt >> 3, qtc = nt & 7;
    if (part == 0) {
#pragma unroll
        for (int round = 0; round < 8; ++round) {
            int r = tid & 127;
            int kc = (tid >> 7) + round * 2;       // 0..15 d-chunk
            uint4 val = *(const uint4*)(smb + r * 256 +
                        (((unsigned)(kc << 4)) ^ ((r & 7) << 4)));
            int h = (mt % 6) * 2 + (kc >> 3);
            int bh = b * H_ + h;
            *(uint4*)(QS + (((size_t)(bh * 8 + qtc) * 1024) + (kc & 7) * 128 + r) * 8) = val;
        }
    } else if (part == 1) {
#pragma unroll
        for (int round = 0; round < 8; ++round) {
            int r = tid & 127;
            int kc = (tid >> 7) + round * 2;
            uint4 val = *(const uint4*)(smb + r * 256 +
                        (((unsigned)(kc << 4)) ^ ((r & 7) << 4)));
            int h = (mt % 6) * 2 + (kc >> 3);
            int bh = b * H_ + h;
            int kt = (qtc << 1) | (r >> 6);
            *(uint4*)(KS + (((size_t)(bh * 16 + kt) * 512) + (kc & 7) * 64 + (r & 63)) * 8) = val;
        }
    } else {
#pragma unroll
        for (int round = 0; round < 8; ++round) {
            int dd = tid & 127;
            int tc = (tid >> 7) + round * 2;       // 0..15 tok-chunk
            uint4 val = *(const uint4*)(smb + dd * 256 +
                        (((unsigned)(tc << 4)) ^ ((dd & 7) << 4)));
            int h = (mt % 6) * 2 + (dd >> 6);
            int bh = b * H_ + h;
            int kt = (qtc << 1) | (tc >> 3);
            *(uint4*)(VS + (((size_t)(bh * 16 + kt) * 512) + (tc & 7) * 64 + (dd & 63)) * 8) = val;
        }
    }
}

// ---------------------------------------------------------------------------
// Flash attention, 32x32 form. S^T = K.Q (pre-scaled Q -> exp2 direct),
// P fragments assembled in-register via permlane32_swap, no P scratch,
// no epilogue LDS. LDS = K dbuf 16 KB + V dbuf 16 KB = 32 KB; Q staged
// through the parity-1 halves before the pipeline starts.
// ---------------------------------------------------------------------------
__global__ __launch_bounds__(256, 3) void attn_kernel(
    const unsigned short* __restrict__ QS,
    const unsigned short* __restrict__ KS,
    const unsigned short* __restrict__ VS,
    unsigned short* __restrict__ AWS)
{
    __shared__ __align__(16) unsigned short sm[16384];  // 32 KB
    // bytes: K dbuf [0,16384) ; V dbuf [16384,32768)
    const int tid = threadIdx.x;
    const int w = tid >> 6, lane = tid & 63;
    const int l31 = lane & 31, h = lane >> 5;
    const int bh = blockIdx.x % 96;
    const int qt = blockIdx.x / 96;

    char* smb = (char*)sm;
    const char* kbase = (const char*)(KS + (size_t)(bh * 16) * 4096);
    const char* vbase = (const char*)(VS + (size_t)(bh * 16) * 4096);

    auto issue_tile = [&](int kt) {
        const char* ks_ = kbase + kt * 8192;
        const char* vs_ = vbase + kt * 8192;
        const int pb = kt & 1;
#pragma unroll
        for (int i = 0; i < 2; ++i) {
            const int c = w * 2 + i;
            gl_lds16(ks_ + (c * 64 + lane) * 16, smb + pb * 8192 + c * 1024);
            gl_lds16(vs_ + (c * 64 + lane) * 16, smb + 16384 + pb * 8192 + c * 1024);
        }
    };

    // stage Q (16 KB) into the dead parity-1 halves: chunks 0-7 -> K pb1,
    // chunks 8-15 -> V pb1. Linear layout preserved within each half.
    const char* qslab = (const char*)(QS + (size_t)(bh * 8 + qt) * 8192);
#pragma unroll
    for (int i = 0; i < 4; ++i) {
        const int c = w * 4 + i;                   // uniform per wave
        char* dst = (c < 8) ? (smb + 8192 + c * 1024)
                            : (smb + 24576 + (c - 8) * 1024);
        gl_lds16(qslab + (c * 64 + lane) * 16, dst);
    }
    issue_tile(0);

    WAITVM(4);                          // Q landed (tile0 still in flight)
    BAR();
    // qf[ks]: B-frag  Q[q = w*32+l31][d = ks*16 + h*8 + {0..7}]
    bf16x8 qf[4];
#pragma unroll
    for (int ks = 0; ks < 4; ++ks) {
        const char* qreg = (ks < 2) ? (smb + 8192) : (smb + 24576);
        const int dcl = (ks & 1) * 2 + h;          // d-chunk within region
        qf[ks] = *(const bf16x8*)(qreg + (dcl * 128 + w * 32 + l31) * 16);
    }
    WAITLGKM();                         // qf in registers on every wave
    // (loop's first BAR makes the Q region safe to overwrite)

    f32x16 acc[2];
    const f32x16 z16 = {0.f,0.f,0.f,0.f,0.f,0.f,0.f,0.f,
                        0.f,0.f,0.f,0.f,0.f,0.f,0.f,0.f};
    acc[0] = z16; acc[1] = z16;
    float lsum = 0.f;

    for (int kt = 0; kt < 16; ++kt) {
        BAR();
        if (kt < 15) { issue_tile(kt + 1); WAITVM(4); } else { WAITVM(0); }
        BAR();
        const char* Kb = smb + (kt & 1) * 8192;
        const char* Vb = smb + 16384 + (kt & 1) * 8192;

        // S^T[key][q]: sv[kb] over d-steps ks. A = K frag, B = Q frag.
        f32x16 sv[2] = {z16, z16};
#pragma unroll
        for (int ks = 0; ks < 4; ++ks) {
#pragma unroll
            for (int kb = 0; kb < 2; ++kb) {
                bf16x8 kf = *(const bf16x8*)(Kb +
                            ((ks * 2 + h) * 64 + kb * 32 + l31) * 16);
                sv[kb] = MFMA32(kf, qf[ks], sv[kb]);
            }
        }

        // softmax + in-register P^T fragment assembly.
        // Lane (half h) holds rows {0-3,8-11,16-19,24-27}+4h of each
        // 32-key block for col q. PV B-frag (step s, half h) needs keys
        // s*16 + h*8 + {0..7}:
        //   s=0 word0 = {h0: own X0, h1: partner Y0} = swap(X0,Y0)[0]
        //   s=0 word2 = {h0: partner X0, h1: own Y0} = swap(X0,Y0)[1]
        //   s=1 word0 = {h0: own Z0, h1: partner W0} = swap(Z0,W0)[0]
        //   s=1 word2 = {h0: partner Z0, h1: own W0} = swap(Z0,W0)[1]
        unsigned pw[4][4];                         // [key-step][word]
#pragma unroll
        for (int kb = 0; kb < 2; ++kb) {
            float p[16];
#pragma unroll
            for (int r = 0; r < 16; ++r)
                p[r] = truncbf(__builtin_amdgcn_exp2f(sv[kb][r]));
            lsum += ((((p[0] + p[1]) + (p[2] + p[3])) +
                      ((p[4] + p[5]) + (p[6] + p[7]))) +
                     (((p[8] + p[9]) + (p[10] + p[11])) +
                      ((p[12] + p[13]) + (p[14] + p[15]))));
            unsigned X0 = pk2t(p[0],  p[1]),  X1 = pk2t(p[2],  p[3]);
            unsigned Y0 = pk2t(p[4],  p[5]),  Y1 = pk2t(p[6],  p[7]);
            unsigned Z0 = pk2t(p[8],  p[9]),  Z1 = pk2t(p[10], p[11]);
            unsigned W0 = pk2t(p[12], p[13]), W1 = pk2t(p[14], p[15]);
            u32x2 a0 = __builtin_amdgcn_permlane32_swap(X0, Y0, false, false);
            u32x2 a1 = __builtin_amdgcn_permlane32_swap(X1, Y1, false, false);
            u32x2 b0 = __builtin_amdgcn_permlane32_swap(Z0, W0, false, false);
            u32x2 b1 = __builtin_amdgcn_permlane32_swap(Z1, W1, false, false);
            pw[kb * 2][0] = a0[0]; pw[kb * 2][1] = a1[0];
            pw[kb * 2][2] = a0[1]; pw[kb * 2][3] = a1[1];
            pw[kb * 2 + 1][0] = b0[0]; pw[kb * 2 + 1][1] = b1[0];
            pw[kb * 2 + 1][2] = b0[1]; pw[kb * 2 + 1][3] = b1[1];
        }

        // out^T += V^T . P^T
#pragma unroll
        for (int ks = 0; ks < 4; ++ks) {
            u32x4 pv = {pw[ks][0], pw[ks][1], pw[ks][2], pw[ks][3]};
            bf16x8 pf = __builtin_bit_cast(bf16x8, pv);
#pragma unroll
            for (int db = 0; db < 2; ++db) {
                bf16x8 vf = *(const bf16x8*)(Vb +
                            ((ks * 2 + h) * 64 + db * 32 + l31) * 16);
                acc[db] = MFMA32(vf, pf, acc[db]);
            }
        }
    }

    // l covers half the keys per lane; partner (^32) has the complement.
    float lfull = lsum + __shfl_xor(lsum, 32, 64);
    float inv = 1.f / lfull;

    // epilogue: permlane32 d-interleave -> direct coalesced uint4 stores.
    // Lane (half h) holds d-rows {0-3,8-11,16-19,24-27}+4h (+32db) for
    // q = w*32+l31. Chunk dc = db*4 + g covers d = 8g+{0..7}+32db:
    //   word0 = {h0: own v00, h1: partner v10} = swap(v00,v10)[0]
    //   word2 = {h0: partner v00, h1: own v10} = swap(v00,v10)[1]
    const int b = bh / H_, hh = bh % H_;
    const int mtA = b * 8 + qt;
    unsigned short* obase = AWS + (size_t)(mtA * 12 + hh) * 8192;
#pragma unroll
    for (int db = 0; db < 2; ++db) {
#pragma unroll
        for (int gp = 0; gp < 2; ++gp) {           // row-group pairs (0,1),(2,3)
            const int g0 = gp * 2, g1 = gp * 2 + 1;
            unsigned v00 = pk2(acc[db][4 * g0 + 0] * inv, acc[db][4 * g0 + 1] * inv);
            unsigned v01 = pk2(acc[db][4 * g0 + 2] * inv, acc[db][4 * g0 + 3] * inv);
            unsigned v10 = pk2(acc[db][4 * g1 + 0] * inv, acc[db][4 * g1 + 1] * inv);
            unsigned v11 = pk2(acc[db][4 * g1 + 2] * inv, acc[db][4 * g1 + 3] * inv);
            u32x2 t0 = __builtin_amdgcn_permlane32_swap(v00, v10, false, false);
            u32x2 t1 = __builtin_amdgcn_permlane32_swap(v01, v11, false, false);
            uint4 val;
            val.x = t0[0]; val.y = t1[0]; val.z = t0[1]; val.w = t1[1];
            const int dc = db * 4 + g0 + h;        // h=0 -> g0, h=1 -> g1
            *(uint4*)(obase + ((size_t)(dc * 128) + w * 32 + l31) * 8) = val;
        }
    }
}

// ---------------------------------------------------------------------------
// proj: C = AWS . WPT + b. Tile 128x64, BK=64 dbuf pipeline (unchanged).
// ---------------------------------------------------------------------------
__global__ __launch_bounds__(256, 3) void proj_gemm(
    const unsigned short* __restrict__ AWS,
    const unsigned short* __restrict__ WPT,
    const float* __restrict__ bias, float* __restrict__ out)
{
    __shared__ __align__(16) unsigned short As[2][8192];
    __shared__ __align__(16) unsigned short Bs[2][4096];

    const int tid = threadIdx.x;
    const int w = tid >> 6, lane = tid & 63;
    const int l15 = lane & 15, quad = lane >> 4;
    const int mt = blockIdx.x / 12;
    const int nt = blockIdx.x % 12;
    const int m0w = (w & 1) * 64, n0w = (w >> 1) * 32;

    const char* baseA = (const char*)(AWS + (size_t)(mt * 12) * 8192);
    const char* baseB = (const char*)(WPT + (size_t)(nt * 12) * 4096);

    auto issue = [&](int ks) {
        const char* sA = baseA + ks * 16384;
        const char* sB = baseB + ks * 8192;
        const int pb = ks & 1;
#pragma unroll
        for (int i = 0; i < 4; ++i) {
            const int c = w * 4 + i;
            gl_lds16(sA + (c * 64 + lane) * 16, (char*)As + pb * 16384 + c * 1024);
        }
#pragma unroll
        for (int i = 0; i < 2; ++i) {
            const int c = w * 2 + i;
            gl_lds16(sB + (c * 64 + lane) * 16, (char*)Bs + pb * 8192 + c * 1024);
        }
    };

    f32x4 acc[4][2];
    const f32x4 z = {0.f, 0.f, 0.f, 0.f};
#pragma unroll
    for (int t = 0; t < 4; ++t) { acc[t][0] = z; acc[t][1] = z; }

    issue(0);
    for (int ks = 0; ks < 12; ++ks) {
        BAR();
        if (ks < 11) { issue(ks + 1); WAITVM(6); } else { WAITVM(0); }
        BAR();
        const unsigned short* Ab = As[ks & 1];
        const unsigned short* Bb = Bs[ks & 1];
#pragma unroll
        for (int kk = 0; kk < 2; ++kk) {
            bf16x8 af[4], bfv[2];
#pragma unroll
            for (int t = 0; t < 4; ++t)
                af[t] = *(const bf16x8*)(Ab + (((kk * 4 + quad) * 128) + m0w + t * 16 + l15) * 8);
#pragma unroll
            for (int u = 0; u < 2; ++u)
                bfv[u] = *(const bf16x8*)(Bb + (((kk * 4 + quad) * 64) + n0w + u * 16 + l15) * 8);
#pragma unroll
            for (int t = 0; t < 4; ++t)
#pragma unroll
                for (int u = 0; u < 2; ++u)
                    acc[t][u] = MFMA(af[t], bfv[u], acc[t][u]);
        }
    }

#pragma unroll
    for (int t = 0; t < 4; ++t)
#pragma unroll
        for (int u = 0; u < 2; ++u) {
            int col = nt * 64 + n0w + u * 16 + l15;
            float bvv = bias[col];
#pragma unroll
            for (int r = 0; r < 4; ++r) {
                int row = mt * 128 + m0w + t * 16 + quad * 4 + r;
                out[(size_t)row * 768 + col] = acc[t][u][r] + bvv;
            }
        }
}

// ---------------------------------------------------------------------------
extern "C" void kernel_launch(void* const* d_in, const int* in_sizes, int n_in,
                              void* d_out, int out_size, void* d_ws, size_t ws_size,
                              hipStream_t stream) {
    const float* x     = (const float*)d_in[0];
    const float* Wqkv  = (const float*)d_in[1];
    const float* bqkv  = (const float*)d_in[2];
    const float* Wproj = (const float*)d_in[3];
    const float* bproj = (const float*)d_in[4];
    float* out = (float*)d_out;

    unsigned short* ws = (unsigned short*)d_ws;
    unsigned short* XB  = ws;                       // 6291456
    unsigned short* WQT = ws + 6291456;             // 1769472
    unsigned short* WPT = ws + 8060928;             // 589824
    unsigned short* QS  = ws + 8650752;             // 6291456
    unsigned short* KS  = ws + 14942208;            // 6291456
    unsigned short* VS  = ws + 21233664;            // 6291456
    unsigned short* AWS = ws + 27525120;            // 6291456

    prep_kernel<<<dim3(4224), dim3(256), 0, stream>>>(x, Wqkv, Wproj, XB, WQT, WPT);
    qkv_gemm<<<dim3(18 * 64), dim3(256), 0, stream>>>(XB, WQT, bqkv, QS, KS, VS);
    attn_kernel<<<dim3(96 * 8), dim3(256), 0, stream>>>(QS, KS, VS, AWS);
    proj_gemm<<<dim3(64 * 12), dim3(256), 0, stream>>>(AWS, WPT, bproj, out);
}

// Round 3
// 174.857 us; speedup vs baseline: 1.0545x; 1.0297x over previous
//
#include <hip/hip_runtime.h>

// MHSA B=8 N=1024 D=768 H=12 Hd=64. Round 11 = round 10 with a deeper
// attention staging pipeline:
//  - K/V triple-buffered (3 slots x (8K K + 8K V) = 48 KB), 2-tile-deep
//    prefetch: tile kt issued at iter kt-2, steady-state WAITVM(8) keeps
//    8 loads/wave in flight across barriers (T3/T4 proper depth; the old
//    1-deep pipeline gave tile kt only ~1 iteration to land vs ~600-900
//    cyc L3 latency -> ~65% stall, MfmaUtil 21%).
//  - Q stages through slot 2 (its first overwrite is tile 2, issued only
//    after the barrier that follows the qf register loads).
//  - s_setprio(1) around QK and PV MFMA clusters (T5; waves are
//    phase-staggered within a block, the regime where it measured +).
// Lane algebra identical to round 10 (verified passing, absmax 0.0022).
// qkv/proj/prep unchanged.

#define B_   8
#define N_   1024
#define D_   768
#define H_   12
#define HD_  64

typedef __attribute__((ext_vector_type(4))) float f32x4;
typedef __attribute__((ext_vector_type(16))) float f32x16;
typedef __attribute__((ext_vector_type(8))) short bf16x8;
typedef __attribute__((ext_vector_type(2))) unsigned int u32x2;
typedef __attribute__((ext_vector_type(4))) unsigned int u32x4;

__device__ __forceinline__ unsigned short f2bf(float f) {
    unsigned int u = __float_as_uint(f);
    u += 0x7fff + ((u >> 16) & 1);            // RNE
    return (unsigned short)(u >> 16);
}
__device__ __forceinline__ unsigned int pk2(float a, float b) {
    return (unsigned int)f2bf(a) | ((unsigned int)f2bf(b) << 16);
}
// truncating bf16 pack via v_perm_b32 (low16 = a, high16 = b)
__device__ __forceinline__ unsigned int pk2t(float a, float b) {
    return __builtin_amdgcn_perm(__float_as_uint(b), __float_as_uint(a), 0x07060302u);
}
__device__ __forceinline__ float truncbf(float f) {
    return __uint_as_float(__float_as_uint(f) & 0xFFFF0000u);
}
__device__ __forceinline__ void gl_lds16(const void* g, void* l) {
    __builtin_amdgcn_global_load_lds(
        (const __attribute__((address_space(1))) unsigned int*)g,
        (__attribute__((address_space(3))) unsigned int*)l, 16, 0, 0);
}
#define MFMA(a, b, c)   __builtin_amdgcn_mfma_f32_16x16x32_bf16(a, b, c, 0, 0, 0)
#define MFMA32(a, b, c) __builtin_amdgcn_mfma_f32_32x32x16_bf16(a, b, c, 0, 0, 0)
#define BAR() do { __asm__ volatile("" ::: "memory"); \
    __builtin_amdgcn_s_barrier(); \
    __asm__ volatile("" ::: "memory"); } while (0)
#define WAITVM(n) do { __asm__ volatile("" ::: "memory"); \
    __builtin_amdgcn_s_waitcnt(0xF70 | (n)); \
    __asm__ volatile("" ::: "memory"); } while (0)
#define WAITLGKM() __asm__ volatile("s_waitcnt lgkmcnt(0)" ::: "memory")

// ---------------------------------------------------------------------------
// prep: XB / WQT / WPT in slab order (unchanged).
// ---------------------------------------------------------------------------
__global__ __launch_bounds__(256) void prep_kernel(
    const float* __restrict__ x, const float* __restrict__ wqkv,
    const float* __restrict__ wproj,
    unsigned short* __restrict__ XB, unsigned short* __restrict__ WQT,
    unsigned short* __restrict__ WPT)
{
    const int bid = blockIdx.x;
    const int tid = threadIdx.x;
    if (bid < 3072) {                       // XB
        int id = bid * 256 + tid;
        int r  = id & 127;
        int kc = (id >> 7) & 7;
        int ks = (id >> 10) % 12;
        int nt = id / 12288;
        const float* src = x + (size_t)(nt * 128 + r) * 768 + ks * 64 + kc * 8;
        float4 f0 = *(const float4*)src;
        float4 f1 = *(const float4*)(src + 4);
        uint4 o;
        o.x = pk2(f0.x, f0.y); o.y = pk2(f0.z, f0.w);
        o.z = pk2(f1.x, f1.y); o.w = pk2(f1.z, f1.w);
        *(uint4*)&XB[(size_t)id * 8] = o;
    } else if (bid < 3936) {                // WQT
        int id = (bid - 3072) * 256 + tid;
        int fr = id & 127;
        int kc = (id >> 7) & 7;
        int ks = (id >> 10) % 12;
        int mt = id / 12288;
        float v[8];
#pragma unroll
        for (int j = 0; j < 8; ++j)
            v[j] = wqkv[(size_t)(ks * 64 + kc * 8 + j) * 2304 + mt * 128 + fr];
        uint4 o;
        o.x = pk2(v[0], v[1]); o.y = pk2(v[2], v[3]);
        o.z = pk2(v[4], v[5]); o.w = pk2(v[6], v[7]);
        *(uint4*)&WQT[(size_t)id * 8] = o;
    } else {                                // WPT
        int id = (bid - 3936) * 256 + tid;
        int fr = id & 63;
        int kc = (id >> 6) & 7;
        int ks = (id >> 9) % 12;
        int nt = id / 6144;
        float v[8];
#pragma unroll
        for (int j = 0; j < 8; ++j)
            v[j] = wproj[(size_t)(ks * 64 + kc * 8 + j) * 768 + nt * 64 + fr];
        uint4 o;
        o.x = pk2(v[0], v[1]); o.y = pk2(v[2], v[3]);
        o.z = pk2(v[4], v[5]); o.w = pk2(v[6], v[7]);
        *(uint4*)&WPT[(size_t)id * 8] = o;
    }
}

// ---------------------------------------------------------------------------
// QKV: C^T = Wt . x ; tile 128x128, BK=32 dbuf pipeline; LDS-transposed
// coalesced epilogue. Q pre-scaled by 0.125*log2(e). (unchanged)
// ---------------------------------------------------------------------------
__global__ __launch_bounds__(256, 4) void qkv_gemm(
    const unsigned short* __restrict__ XB,
    const unsigned short* __restrict__ WQT,
    const float* __restrict__ bias,
    unsigned short* __restrict__ QS,   // [bh][qt] slab(128), k=d (scaled)
    unsigned short* __restrict__ KS,   // [bh][kt] slab(64), k=d
    unsigned short* __restrict__ VS)   // [bh][kt] slab(64): rows=d, k=key
{
    __shared__ __align__(16) unsigned short sm[16384];  // 32 KB

    const int tid = threadIdx.x;
    const int w = tid >> 6, lane = tid & 63;
    const int l15 = lane & 15, quad = lane >> 4;
    const int mt = blockIdx.x >> 6;   // 0..17 feat tile
    const int nt = blockIdx.x & 63;   // 0..63 token tile
    const int m0w = (w & 1) * 64, n0w = (w >> 1) * 64;
    const float CS = 0.18033688f;     // 0.125 * log2(e)

    char* smb = (char*)sm;
    const char* baseA = (const char*)(WQT + (size_t)(mt * 12) * 8192);
    const char* baseB = (const char*)(XB  + (size_t)(nt * 12) * 8192);

    auto issue = [&](int ks) {
        const char* sA = baseA + ks * 8192;
        const char* sB = baseB + ks * 8192;
        const int pb = ks & 1;
#pragma unroll
        for (int i = 0; i < 2; ++i) {
            const int c = w * 2 + i;
            gl_lds16(sA + (c * 64 + lane) * 16, smb + pb * 8192 + c * 1024);
            gl_lds16(sB + (c * 64 + lane) * 16, smb + 16384 + pb * 8192 + c * 1024);
        }
    };

    f32x4 acc[4][4];
    const f32x4 z = {0.f, 0.f, 0.f, 0.f};
#pragma unroll
    for (int t = 0; t < 4; ++t)
#pragma unroll
        for (int u = 0; u < 4; ++u) acc[t][u] = z;

    issue(0);
    for (int ks = 0; ks < 24; ++ks) {
        BAR();
        if (ks < 23) { issue(ks + 1); WAITVM(4); } else { WAITVM(0); }
        BAR();
        const unsigned short* Ab = sm + (ks & 1) * 4096;
        const unsigned short* Bb = sm + 8192 + (ks & 1) * 4096;
        bf16x8 af[4], bfv[4];
#pragma unroll
        for (int t = 0; t < 4; ++t)
            af[t] = *(const bf16x8*)(Ab + (quad * 128 + m0w + t * 16 + l15) * 8);
#pragma unroll
        for (int u = 0; u < 4; ++u)
            bfv[u] = *(const bf16x8*)(Bb + (quad * 128 + n0w + u * 16 + l15) * 8);
#pragma unroll
        for (int t = 0; t < 4; ++t)
#pragma unroll
            for (int u = 0; u < 4; ++u)
                acc[t][u] = MFMA(af[t], bfv[u], acc[t][u]);
    }

    const int part = mt / 6;   // 0=Q 1=K 2=V (uniform per block)
    BAR();                     // all waves done with staged LDS

    // ---- write accumulators to swizzled LDS tile ----
#pragma unroll
    for (int t = 0; t < 4; ++t) {
        int d = m0w + t * 16 + quad * 4;          // feat-in-tile 0..127
        float4 bv = *(const float4*)&bias[part * 768 + (mt % 6) * 128 + d];
#pragma unroll
        for (int u = 0; u < 4; ++u) {
            int tok = n0w + u * 16 + l15;         // tok-in-tile 0..127
            f32x4 a = acc[t][u];
            float v0 = a[0] + bv.x, v1 = a[1] + bv.y;
            float v2 = a[2] + bv.z, v3 = a[3] + bv.w;
            if (part == 0) { v0 *= CS; v1 *= CS; v2 *= CS; v3 *= CS; }
            if (part < 2) {
                unsigned off = tok * 256 + (((unsigned)(d * 2)) ^ ((tok & 7) << 4));
                uint2 pp; pp.x = pk2(v0, v1); pp.y = pk2(v2, v3);
                *(uint2*)(smb + off) = pp;
            } else {
                float vv[4] = {v0, v1, v2, v3};
#pragma unroll
                for (int r4 = 0; r4 < 4; ++r4) {
                    int dd = d + r4;
                    unsigned off = dd * 256 + (((unsigned)(tok * 2)) ^ ((dd & 7) << 4));
                    *(unsigned short*)(smb + off) = f2bf(vv[r4]);
                }
            }
        }
    }
    BAR();

    // ---- coalesced read-out + global store ----
    const int b = nt >> 3, qtc = nt & 7;
    if (part == 0) {
#pragma unroll
        for (int round = 0; round < 8; ++round) {
            int r = tid & 127;
            int kc = (tid >> 7) + round * 2;       // 0..15 d-chunk
            uint4 val = *(const uint4*)(smb + r * 256 +
                        (((unsigned)(kc << 4)) ^ ((r & 7) << 4)));
            int h = (mt % 6) * 2 + (kc >> 3);
            int bh = b * H_ + h;
            *(uint4*)(QS + (((size_t)(bh * 8 + qtc) * 1024) + (kc & 7) * 128 + r) * 8) = val;
        }
    } else if (part == 1) {
#pragma unroll
        for (int round = 0; round < 8; ++round) {
            int r = tid & 127;
            int kc = (tid >> 7) + round * 2;
            uint4 val = *(const uint4*)(smb + r * 256 +
                        (((unsigned)(kc << 4)) ^ ((r & 7) << 4)));
            int h = (mt % 6) * 2 + (kc >> 3);
            int bh = b * H_ + h;
            int kt = (qtc << 1) | (r >> 6);
            *(uint4*)(KS + (((size_t)(bh * 16 + kt) * 512) + (kc & 7) * 64 + (r & 63)) * 8) = val;
        }
    } else {
#pragma unroll
        for (int round = 0; round < 8; ++round) {
            int dd = tid & 127;
            int tc = (tid >> 7) + round * 2;       // 0..15 tok-chunk
            uint4 val = *(const uint4*)(smb + dd * 256 +
                        (((unsigned)(tc << 4)) ^ ((dd & 7) << 4)));
            int h = (mt % 6) * 2 + (dd >> 6);
            int bh = b * H_ + h;
            int kt = (qtc << 1) | (tc >> 3);
            *(uint4*)(VS + (((size_t)(bh * 16 + kt) * 512) + (tc & 7) * 64 + (dd & 63)) * 8) = val;
        }
    }
}

// ---------------------------------------------------------------------------
// Flash attention, 32x32 form. S^T = K.Q (pre-scaled Q -> exp2 direct),
// P fragments assembled in-register via permlane32_swap, no P scratch,
// no epilogue LDS. K/V triple-buffered (48 KB), 2-tile-deep prefetch;
// Q staged through slot 2 before the rotation reaches it.
// ---------------------------------------------------------------------------
__global__ __launch_bounds__(256, 3) void attn_kernel(
    const unsigned short* __restrict__ QS,
    const unsigned short* __restrict__ KS,
    const unsigned short* __restrict__ VS,
    unsigned short* __restrict__ AWS)
{
    __shared__ __align__(16) unsigned short sm[24576];  // 48 KB
    // bytes: K slots [0,24576) ; V slots [24576,49152) ; slot s at +s*8192
    const int tid = threadIdx.x;
    const int w = tid >> 6, lane = tid & 63;
    const int l31 = lane & 31, h = lane >> 5;
    const int bh = blockIdx.x % 96;
    const int qt = blockIdx.x / 96;

    char* smb = (char*)sm;
    const char* kbase = (const char*)(KS + (size_t)(bh * 16) * 4096);
    const char* vbase = (const char*)(VS + (size_t)(bh * 16) * 4096);

    auto issue_tile = [&](int kt) {
        const char* ks_ = kbase + kt * 8192;
        const char* vs_ = vbase + kt * 8192;
        const int sl = kt % 3;
#pragma unroll
        for (int i = 0; i < 2; ++i) {
            const int c = w * 2 + i;
            gl_lds16(ks_ + (c * 64 + lane) * 16, smb + sl * 8192 + c * 1024);
            gl_lds16(vs_ + (c * 64 + lane) * 16, smb + 24576 + sl * 8192 + c * 1024);
        }
    };

    // stage Q (16 KB) into slot 2: chunks 0-7 -> K slot2, 8-15 -> V slot2.
    const char* qslab = (const char*)(QS + (size_t)(bh * 8 + qt) * 8192);
#pragma unroll
    for (int i = 0; i < 4; ++i) {
        const int c = w * 4 + i;                   // uniform per wave
        char* dst = (c < 8) ? (smb + 16384 + c * 1024)
                            : (smb + 40960 + (c - 8) * 1024);
        gl_lds16(qslab + (c * 64 + lane) * 16, dst);
    }
    issue_tile(0);
    issue_tile(1);

    WAITVM(8);                          // Q landed (tiles 0,1 in flight)
    BAR();
    // qf[ks]: B-frag  Q[q = w*32+l31][d = ks*16 + h*8 + {0..7}]
    bf16x8 qf[4];
#pragma unroll
    for (int ks = 0; ks < 4; ++ks) {
        const char* qreg = (ks < 2) ? (smb + 16384) : (smb + 40960);
        const int dcl = (ks & 1) * 2 + h;          // d-chunk within region
        qf[ks] = *(const bf16x8*)(qreg + (dcl * 128 + w * 32 + l31) * 16);
    }
    WAITLGKM();                         // qf in registers on every wave
    // (loop's first BAR makes slot 2 safe to overwrite at kt=0)

    f32x16 acc[2];
    const f32x16 z16 = {0.f,0.f,0.f,0.f,0.f,0.f,0.f,0.f,
                        0.f,0.f,0.f,0.f,0.f,0.f,0.f,0.f};
    acc[0] = z16; acc[1] = z16;
    float lsum = 0.f;

    for (int kt = 0; kt < 16; ++kt) {
        BAR();                          // all waves done with slot (kt+2)%3
        if (kt < 14)      { issue_tile(kt + 2); WAITVM(8); }
        else if (kt == 14){ WAITVM(4); }
        else              { WAITVM(0); }
        BAR();                          // tile kt landed on all waves
        const char* Kb = smb + (kt % 3) * 8192;
        const char* Vb = smb + 24576 + (kt % 3) * 8192;

        // S^T[key][q]: sv[kb] over d-steps ks. A = K frag, B = Q frag.
        f32x16 sv[2] = {z16, z16};
        __builtin_amdgcn_s_setprio(1);
#pragma unroll
        for (int ks = 0; ks < 4; ++ks) {
#pragma unroll
            for (int kb = 0; kb < 2; ++kb) {
                bf16x8 kf = *(const bf16x8*)(Kb +
                            ((ks * 2 + h) * 64 + kb * 32 + l31) * 16);
                sv[kb] = MFMA32(kf, qf[ks], sv[kb]);
            }
        }
        __builtin_amdgcn_s_setprio(0);

        // softmax + in-register P^T fragment assembly.
        // Lane (half h) holds rows {0-3,8-11,16-19,24-27}+4h of each
        // 32-key block for col q. PV B-frag (step s, half h) needs keys
        // s*16 + h*8 + {0..7}:
        //   s=0 word0 = swap(X0,Y0)[0], word2 = swap(X0,Y0)[1]
        //   s=1 word0 = swap(Z0,W0)[0], word2 = swap(Z0,W0)[1]
        unsigned pw[4][4];                         // [key-step][word]
#pragma unroll
        for (int kb = 0; kb < 2; ++kb) {
            float p[16];
#pragma unroll
            for (int r = 0; r < 16; ++r)
                p[r] = truncbf(__builtin_amdgcn_exp2f(sv[kb][r]));
            lsum += ((((p[0] + p[1]) + (p[2] + p[3])) +
                      ((p[4] + p[5]) + (p[6] + p[7]))) +
                     (((p[8] + p[9]) + (p[10] + p[11])) +
                      ((p[12] + p[13]) + (p[14] + p[15]))));
            unsigned X0 = pk2t(p[0],  p[1]),  X1 = pk2t(p[2],  p[3]);
            unsigned Y0 = pk2t(p[4],  p[5]),  Y1 = pk2t(p[6],  p[7]);
            unsigned Z0 = pk2t(p[8],  p[9]),  Z1 = pk2t(p[10], p[11]);
            unsigned W0 = pk2t(p[12], p[13]), W1 = pk2t(p[14], p[15]);
            u32x2 a0 = __builtin_amdgcn_permlane32_swap(X0, Y0, false, false);
            u32x2 a1 = __builtin_amdgcn_permlane32_swap(X1, Y1, false, false);
            u32x2 b0 = __builtin_amdgcn_permlane32_swap(Z0, W0, false, false);
            u32x2 b1 = __builtin_amdgcn_permlane32_swap(Z1, W1, false, false);
            pw[kb * 2][0] = a0[0]; pw[kb * 2][1] = a1[0];
            pw[kb * 2][2] = a0[1]; pw[kb * 2][3] = a1[1];
            pw[kb * 2 + 1][0] = b0[0]; pw[kb * 2 + 1][1] = b1[0];
            pw[kb * 2 + 1][2] = b0[1]; pw[kb * 2 + 1][3] = b1[1];
        }

        // out^T += V^T . P^T
        __builtin_amdgcn_s_setprio(1);
#pragma unroll
        for (int ks = 0; ks < 4; ++ks) {
            u32x4 pv = {pw[ks][0], pw[ks][1], pw[ks][2], pw[ks][3]};
            bf16x8 pf = __builtin_bit_cast(bf16x8, pv);
#pragma unroll
            for (int db = 0; db < 2; ++db) {
                bf16x8 vf = *(const bf16x8*)(Vb +
                            ((ks * 2 + h) * 64 + db * 32 + l31) * 16);
                acc[db] = MFMA32(vf, pf, acc[db]);
            }
        }
        __builtin_amdgcn_s_setprio(0);
    }

    // l covers half the keys per lane; partner (^32) has the complement.
    float lfull = lsum + __shfl_xor(lsum, 32, 64);
    float inv = 1.f / lfull;

    // epilogue: permlane32 d-interleave -> direct coalesced uint4 stores.
    // Lane (half h) holds d-rows {0-3,8-11,16-19,24-27}+4h (+32db) for
    // q = w*32+l31. Chunk dc = db*4 + g covers d = 8g+{0..7}+32db:
    //   word0 = swap(v00,v10)[0], word2 = swap(v00,v10)[1]
    const int b = bh / H_, hh = bh % H_;
    const int mtA = b * 8 + qt;
    unsigned short* obase = AWS + (size_t)(mtA * 12 + hh) * 8192;
#pragma unroll
    for (int db = 0; db < 2; ++db) {
#pragma unroll
        for (int gp = 0; gp < 2; ++gp) {           // row-group pairs (0,1),(2,3)
            const int g0 = gp * 2, g1 = gp * 2 + 1;
            unsigned v00 = pk2(acc[db][4 * g0 + 0] * inv, acc[db][4 * g0 + 1] * inv);
            unsigned v01 = pk2(acc[db][4 * g0 + 2] * inv, acc[db][4 * g0 + 3] * inv);
            unsigned v10 = pk2(acc[db][4 * g1 + 0] * inv, acc[db][4 * g1 + 1] * inv);
            unsigned v11 = pk2(acc[db][4 * g1 + 2] * inv, acc[db][4 * g1 + 3] * inv);
            u32x2 t0 = __builtin_amdgcn_permlane32_swap(v00, v10, false, false);
            u32x2 t1 = __builtin_amdgcn_permlane32_swap(v01, v11, false, false);
            uint4 val;
            val.x = t0[0]; val.y = t1[0]; val.z = t0[1]; val.w = t1[1];
            const int dc = db * 4 + g0 + h;        // h=0 -> g0, h=1 -> g1
            *(uint4*)(obase + ((size_t)(dc * 128) + w * 32 + l31) * 8) = val;
        }
    }
}

// ---------------------------------------------------------------------------
// proj: C = AWS . WPT + b. Tile 128x64, BK=64 dbuf pipeline (unchanged).
// ---------------------------------------------------------------------------
__global__ __launch_bounds__(256, 3) void proj_gemm(
    const unsigned short* __restrict__ AWS,
    const unsigned short* __restrict__ WPT,
    const float* __restrict__ bias, float* __restrict__ out)
{
    __shared__ __align__(16) unsigned short As[2][8192];
    __shared__ __align__(16) unsigned short Bs[2][4096];

    const int tid = threadIdx.x;
    const int w = tid >> 6, lane = tid & 63;
    const int l15 = lane & 15, quad = lane >> 4;
    const int mt = blockIdx.x / 12;
    const int nt = blockIdx.x % 12;
    const int m0w = (w & 1) * 64, n0w = (w >> 1) * 32;

    const char* baseA = (const char*)(AWS + (size_t)(mt * 12) * 8192);
    const char* baseB = (const char*)(WPT + (size_t)(nt * 12) * 4096);

    auto issue = [&](int ks) {
        const char* sA = baseA + ks * 16384;
        const char* sB = baseB + ks * 8192;
        const int pb = ks & 1;
#pragma unroll
        for (int i = 0; i < 4; ++i) {
            const int c = w * 4 + i;
            gl_lds16(sA + (c * 64 + lane) * 16, (char*)As + pb * 16384 + c * 1024);
        }
#pragma unroll
        for (int i = 0; i < 2; ++i) {
            const int c = w * 2 + i;
            gl_lds16(sB + (c * 64 + lane) * 16, (char*)Bs + pb * 8192 + c * 1024);
        }
    };

    f32x4 acc[4][2];
    const f32x4 z = {0.f, 0.f, 0.f, 0.f};
#pragma unroll
    for (int t = 0; t < 4; ++t) { acc[t][0] = z; acc[t][1] = z; }

    issue(0);
    for (int ks = 0; ks < 12; ++ks) {
        BAR();
        if (ks < 11) { issue(ks + 1); WAITVM(6); } else { WAITVM(0); }
        BAR();
        const unsigned short* Ab = As[ks & 1];
        const unsigned short* Bb = Bs[ks & 1];
#pragma unroll
        for (int kk = 0; kk < 2; ++kk) {
            bf16x8 af[4], bfv[2];
#pragma unroll
            for (int t = 0; t < 4; ++t)
                af[t] = *(const bf16x8*)(Ab + (((kk * 4 + quad) * 128) + m0w + t * 16 + l15) * 8);
#pragma unroll
            for (int u = 0; u < 2; ++u)
                bfv[u] = *(const bf16x8*)(Bb + (((kk * 4 + quad) * 64) + n0w + u * 16 + l15) * 8);
#pragma unroll
            for (int t = 0; t < 4; ++t)
#pragma unroll
                for (int u = 0; u < 2; ++u)
                    acc[t][u] = MFMA(af[t], bfv[u], acc[t][u]);
        }
    }

#pragma unroll
    for (int t = 0; t < 4; ++t)
#pragma unroll
        for (int u = 0; u < 2; ++u) {
            int col = nt * 64 + n0w + u * 16 + l15;
            float bvv = bias[col];
#pragma unroll
            for (int r = 0; r < 4; ++r) {
                int row = mt * 128 + m0w + t * 16 + quad * 4 + r;
                out[(size_t)row * 768 + col] = acc[t][u][r] + bvv;
            }
        }
}

// ---------------------------------------------------------------------------
extern "C" void kernel_launch(void* const* d_in, const int* in_sizes, int n_in,
                              void* d_out, int out_size, void* d_ws, size_t ws_size,
                              hipStream_t stream) {
    const float* x     = (const float*)d_in[0];
    const float* Wqkv  = (const float*)d_in[1];
    const float* bqkv  = (const float*)d_in[2];
    const float* Wproj = (const float*)d_in[3];
    const float* bproj = (const float*)d_in[4];
    float* out = (float*)d_out;

    unsigned short* ws = (unsigned short*)d_ws;
    unsigned short* XB  = ws;                       // 6291456
    unsigned short* WQT = ws + 6291456;             // 1769472
    unsigned short* WPT = ws + 8060928;             // 589824
    unsigned short* QS  = ws + 8650752;             // 6291456
    unsigned short* KS  = ws + 14942208;            // 6291456
    unsigned short* VS  = ws + 21233664;            // 6291456
    unsigned short* AWS = ws + 27525120;            // 6291456

    prep_kernel<<<dim3(4224), dim3(256), 0, stream>>>(x, Wqkv, Wproj, XB, WQT, WPT);
    qkv_gemm<<<dim3(18 * 64), dim3(256), 0, stream>>>(XB, WQT, bqkv, QS, KS, VS);
    attn_kernel<<<dim3(96 * 8), dim3(256), 0, stream>>>(QS, KS, VS, AWS);
    proj_gemm<<<dim3(64 * 12), dim3(256), 0, stream>>>(AWS, WPT, bproj, out);
}